// Round 1
// baseline (306.943 us; speedup 1.0000x reference)
//
#include <hip/hip_runtime.h>
#include <hip/hip_bf16.h>

typedef _Float16 __attribute__((ext_vector_type(8))) half8;
typedef float __attribute__((ext_vector_type(4))) f32x4;

typedef __attribute__((address_space(1))) void gvoid_t;
typedef __attribute__((address_space(3))) void lvoid_t;

__device__ __forceinline__ void gld_lds16(const void* g, void* l) {
    __builtin_amdgcn_global_load_lds((const gvoid_t*)g, (lvoid_t*)l, 16, 0, 0);
}

// ---------------- f32 -> f16 convert ----------------
__global__ void cvt_f32_to_f16(const float* __restrict__ in, _Float16* __restrict__ out, int n) {
    int i = (blockIdx.x * 256 + threadIdx.x) * 8;
    if (i >= n) return;
    float4 a = *(const float4*)(in + i);
    float4 b = *(const float4*)(in + i + 4);
    half8 h;
    h[0] = (_Float16)a.x; h[1] = (_Float16)a.y; h[2] = (_Float16)a.z; h[3] = (_Float16)a.w;
    h[4] = (_Float16)b.x; h[5] = (_Float16)b.y; h[6] = (_Float16)b.z; h[7] = (_Float16)b.w;
    *(half8*)(out + i) = h;
}

// ---------------- GEMM: C[m,n] = sum_k A[m,k]*W[n,k] + bias[n] ----------------
// A: MxK f16 row-major; W: NxK f16 row-major (i.e. B^T input); C: MxN.
template <typename OutT>
__global__ __launch_bounds__(256) void gemm_bt(
    const _Float16* __restrict__ A,
    const _Float16* __restrict__ W,
    const float* __restrict__ bias,
    OutT* __restrict__ C,
    int M, int N, int K)
{
    __shared__ _Float16 As[128 * 64];
    __shared__ _Float16 Bs[128 * 64];
    const int tid = threadIdx.x;
    const int wv = tid >> 6;
    const int lane = tid & 63;
    const int lr = lane & 15;   // row-in-16 (A) / col (B,C)
    const int lk = lane >> 4;   // k-group / row-group (C)
    const int wm = wv >> 1, wn = wv & 1;
    const int nbn = N >> 7;
    const int bm = blockIdx.x / nbn, bn = blockIdx.x % nbn;

    f32x4 acc[4][4] = {};

    for (int k0 = 0; k0 < K; k0 += 64) {
        __syncthreads();  // prior-iter LDS reads done before overwrite
#pragma unroll
        for (int i = 0; i < 4; ++i) {
            int chunk = i * 256 + tid;          // 0..1023, linear in LDS
            int row = chunk >> 3, c8 = chunk & 7;
            gld_lds16(A + (size_t)(bm * 128 + row) * K + k0 + c8 * 8, &As[chunk * 8]);
        }
#pragma unroll
        for (int i = 0; i < 4; ++i) {
            int chunk = i * 256 + tid;
            int row = chunk >> 3, c8 = chunk & 7;
            gld_lds16(W + (size_t)(bn * 128 + row) * K + k0 + c8 * 8, &Bs[chunk * 8]);
        }
        __syncthreads();  // vmcnt drained here by compiler

#pragma unroll
        for (int kk = 0; kk < 2; ++kk) {
            half8 a[4], b[4];
#pragma unroll
            for (int m = 0; m < 4; ++m)
                a[m] = *(const half8*)&As[(wm * 64 + m * 16 + lr) * 64 + kk * 32 + lk * 8];
#pragma unroll
            for (int n = 0; n < 4; ++n)
                b[n] = *(const half8*)&Bs[(wn * 64 + n * 16 + lr) * 64 + kk * 32 + lk * 8];
#pragma unroll
            for (int m = 0; m < 4; ++m)
#pragma unroll
                for (int n = 0; n < 4; ++n)
                    acc[m][n] = __builtin_amdgcn_mfma_f32_16x16x32_f16(a[m], b[n], acc[m][n], 0, 0, 0);
        }
    }

#pragma unroll
    for (int m = 0; m < 4; ++m) {
#pragma unroll
        for (int n = 0; n < 4; ++n) {
            int row0 = bm * 128 + wm * 64 + m * 16 + lk * 4;
            int col  = bn * 128 + wn * 64 + n * 16 + lr;
            float bb = bias[col];
#pragma unroll
            for (int r = 0; r < 4; ++r) {
                float v = acc[m][n][r] + bb;
                C[(size_t)(row0 + r) * N + col] = (OutT)v;
            }
        }
    }
}

// ---------------- Flash attention ----------------
// Q,K,V: (B*L, 1024) f16, head h at cols [h*64, h*64+64). O: same layout, f16.
// grid: (L/64, B*H); 256 threads = 4 waves; wave w owns q-rows [qb*64+w*16, +16).
__global__ __launch_bounds__(256) void attn_fwd(
    const _Float16* __restrict__ Q,
    const _Float16* __restrict__ Kt,
    const _Float16* __restrict__ V,
    _Float16* __restrict__ O)
{
    constexpr int KT = 128;
    __shared__ _Float16 Ks[KT * 64];          // [kv][dh]
    __shared__ _Float16 Vt[64 * (KT + 8)];    // [dh][kv] transposed, padded
    __shared__ _Float16 Ps[4][16 * KT];       // per-wave P tile [q16][kv]

    const int tid = threadIdx.x;
    const int wv = tid >> 6;
    const int lane = tid & 63;
    const int lr = lane & 15;
    const int lk = lane >> 4;
    const int qb = blockIdx.x;
    const int bh = blockIdx.y;
    const size_t base = (size_t)(bh >> 4) * 2048 * 1024 + (size_t)(bh & 15) * 64;

    half8 qf[2];
    {
        const _Float16* qp = Q + base + (size_t)(qb * 64 + wv * 16 + lr) * 1024 + lk * 8;
        qf[0] = *(const half8*)qp;
        qf[1] = *(const half8*)(qp + 32);
    }

    float mr[4], ls[4];
    f32x4 o[4] = {};
#pragma unroll
    for (int r = 0; r < 4; ++r) { mr[r] = -1e30f; ls[r] = 0.f; }

    for (int kt = 0; kt < 2048; kt += KT) {
        __syncthreads();  // prior-iter LDS reads done
        // stage K tile (row-major) via async global->LDS
#pragma unroll
        for (int i = 0; i < 4; ++i) {
            int chunk = i * 256 + tid;
            int row = chunk >> 3, c8 = chunk & 7;
            gld_lds16(Kt + base + (size_t)(kt + row) * 1024 + c8 * 8, &Ks[chunk * 8]);
        }
        // stage V transposed via registers
        half8 vr[4];
#pragma unroll
        for (int i = 0; i < 4; ++i) {
            int chunk = i * 256 + tid;
            int row = chunk >> 3, c8 = chunk & 7;
            vr[i] = *(const half8*)(V + base + (size_t)(kt + row) * 1024 + c8 * 8);
        }
#pragma unroll
        for (int i = 0; i < 4; ++i) {
            int chunk = i * 256 + tid;
            int row = chunk >> 3, c8 = chunk & 7;
#pragma unroll
            for (int j = 0; j < 8; ++j)
                Vt[(c8 * 8 + j) * (KT + 8) + row] = vr[i][j];
        }
        __syncthreads();  // K + Vt staged

        // S = Q K^T  (S row = q = lk*4+reg, col = kv = n*16+lr)
        f32x4 s[8] = {};
#pragma unroll
        for (int kk = 0; kk < 2; ++kk) {
#pragma unroll
            for (int n = 0; n < 8; ++n) {
                half8 b = *(const half8*)&Ks[(n * 16 + lr) * 64 + kk * 32 + lk * 8];
                s[n] = __builtin_amdgcn_mfma_f32_16x16x32_f16(qf[kk], b, s[n], 0, 0, 0);
            }
        }
        // scale + row max
        float tm[4];
#pragma unroll
        for (int r = 0; r < 4; ++r) tm[r] = -1e30f;
#pragma unroll
        for (int n = 0; n < 8; ++n)
#pragma unroll
            for (int r = 0; r < 4; ++r) {
                float v = s[n][r] * 0.125f;
                s[n][r] = v;
                tm[r] = fmaxf(tm[r], v);
            }
#pragma unroll
        for (int off = 1; off < 16; off <<= 1)
#pragma unroll
            for (int r = 0; r < 4; ++r)
                tm[r] = fmaxf(tm[r], __shfl_xor(tm[r], off));

        float al[4], rs[4];
#pragma unroll
        for (int r = 0; r < 4; ++r) {
            float mn = fmaxf(mr[r], tm[r]);
            al[r] = __expf(mr[r] - mn);
            mr[r] = mn;
            rs[r] = 0.f;
        }
        // P = exp(S - m), write to LDS (bf-roundtrip for PV MFMA A-operand)
#pragma unroll
        for (int n = 0; n < 8; ++n)
#pragma unroll
            for (int r = 0; r < 4; ++r) {
                float p = __expf(s[n][r] - mr[r]);
                rs[r] += p;
                Ps[wv][(lk * 4 + r) * KT + n * 16 + lr] = (_Float16)p;
            }
#pragma unroll
        for (int off = 1; off < 16; off <<= 1)
#pragma unroll
            for (int r = 0; r < 4; ++r)
                rs[r] += __shfl_xor(rs[r], off);
#pragma unroll
        for (int r = 0; r < 4; ++r) ls[r] = ls[r] * al[r] + rs[r];
#pragma unroll
        for (int nd = 0; nd < 4; ++nd)
#pragma unroll
            for (int r = 0; r < 4; ++r) o[nd][r] *= al[r];

        // O += P * V   (A-frag from Ps, wave-local; B-frag from Vt contiguous)
#pragma unroll
        for (int kk = 0; kk < 4; ++kk) {
            half8 pa = *(const half8*)&Ps[wv][lr * KT + kk * 32 + lk * 8];
#pragma unroll
            for (int nd = 0; nd < 4; ++nd) {
                half8 bv = *(const half8*)&Vt[(nd * 16 + lr) * (KT + 8) + kk * 32 + lk * 8];
                o[nd] = __builtin_amdgcn_mfma_f32_16x16x32_f16(pa, bv, o[nd], 0, 0, 0);
            }
        }
    }

#pragma unroll
    for (int nd = 0; nd < 4; ++nd) {
        int col = nd * 16 + lr;
#pragma unroll
        for (int r = 0; r < 4; ++r) {
            int qrow = qb * 64 + wv * 16 + lk * 4 + r;
            float val = o[nd][r] / ls[r];
            O[base + (size_t)qrow * 1024 + col] = (_Float16)val;
        }
    }
}

extern "C" void kernel_launch(void* const* d_in, const int* in_sizes, int n_in,
                              void* d_out, int out_size, void* d_ws, size_t ws_size,
                              hipStream_t stream) {
    const float* x_q  = (const float*)d_in[0];
    const float* x_kv = (const float*)d_in[1];
    const float* wq   = (const float*)d_in[2];
    const float* bq   = (const float*)d_in[3];
    const float* wk   = (const float*)d_in[4];
    const float* bk   = (const float*)d_in[5];
    const float* wvp  = (const float*)d_in[6];
    const float* bv   = (const float*)d_in[7];
    const float* wo   = (const float*)d_in[8];
    const float* bo   = (const float*)d_in[9];
    float* out = (float*)d_out;

    const size_t MX = (size_t)4096 * 1024;  // 4M elems
    const size_t WX = (size_t)1024 * 1024;  // 1M elems
    _Float16* ws    = (_Float16*)d_ws;
    _Float16* xq16  = ws;
    _Float16* xkv16 = xq16 + MX;
    _Float16* wq16  = xkv16 + MX;
    _Float16* wk16  = wq16 + WX;
    _Float16* wv16  = wk16 + WX;
    _Float16* wo16  = wv16 + WX;
    _Float16* Qb    = wo16 + WX;
    _Float16* Kb    = Qb + MX;
    _Float16* Vb    = Kb + MX;
    _Float16* AO    = Vb + MX;

    cvt_f32_to_f16<<<MX / 2048, 256, 0, stream>>>(x_q, xq16, (int)MX);
    cvt_f32_to_f16<<<MX / 2048, 256, 0, stream>>>(x_kv, xkv16, (int)MX);
    cvt_f32_to_f16<<<WX / 2048, 256, 0, stream>>>(wq, wq16, (int)WX);
    cvt_f32_to_f16<<<WX / 2048, 256, 0, stream>>>(wk, wk16, (int)WX);
    cvt_f32_to_f16<<<WX / 2048, 256, 0, stream>>>(wvp, wv16, (int)WX);
    cvt_f32_to_f16<<<WX / 2048, 256, 0, stream>>>(wo, wo16, (int)WX);

    // Q/K/V projections (M=4096, N=1024, K=1024), f16 outputs
    gemm_bt<_Float16><<<dim3(32 * 8), 256, 0, stream>>>(xq16,  wq16, bq, Qb, 4096, 1024, 1024);
    gemm_bt<_Float16><<<dim3(32 * 8), 256, 0, stream>>>(xkv16, wk16, bk, Kb, 4096, 1024, 1024);
    gemm_bt<_Float16><<<dim3(32 * 8), 256, 0, stream>>>(xkv16, wv16, bv, Vb, 4096, 1024, 1024);

    // attention
    attn_fwd<<<dim3(32, 32), 256, 0, stream>>>(Qb, Kb, Vb, AO);

    // output projection, fp32 out
    gemm_bt<float><<<dim3(32 * 8), 256, 0, stream>>>(AO, wo16, bo, out, 4096, 1024, 1024);
}

// Round 5
// 201.038 us; speedup vs baseline: 1.5268x; 1.5268x over previous
//
#include <hip/hip_runtime.h>
#include <hip/hip_bf16.h>

typedef _Float16 __attribute__((ext_vector_type(8))) half8;
typedef _Float16 __attribute__((ext_vector_type(4))) half4;
typedef float __attribute__((ext_vector_type(4))) f32x4;

typedef __attribute__((address_space(1))) void gvoid_t;
typedef __attribute__((address_space(3))) void lvoid_t;

__device__ __forceinline__ void gld_lds16(const void* g, void* l) {
    __builtin_amdgcn_global_load_lds((const gvoid_t*)g, (lvoid_t*)l, 16, 0, 0);
}

// ---------------- f32 -> f16 convert, all 6 tensors in one launch ----------------
__global__ void cvt_all(const float* __restrict__ x_q, const float* __restrict__ x_kv,
                        const float* __restrict__ wq, const float* __restrict__ wk,
                        const float* __restrict__ wv, const float* __restrict__ wo,
                        _Float16* __restrict__ xq16, _Float16* __restrict__ xkv16,
                        _Float16* __restrict__ wq16, _Float16* __restrict__ wk16,
                        _Float16* __restrict__ wv16, _Float16* __restrict__ wo16)
{
    const int y = blockIdx.y;
    const int n = (y < 2) ? (4096 * 1024) : (1024 * 1024);
    int i = (blockIdx.x * 256 + threadIdx.x) * 8;
    if (i >= n) return;
    const float* in = (y == 0) ? x_q : (y == 1) ? x_kv : (y == 2) ? wq : (y == 3) ? wk : (y == 4) ? wv : wo;
    _Float16* out = (y == 0) ? xq16 : (y == 1) ? xkv16 : (y == 2) ? wq16 : (y == 3) ? wk16 : (y == 4) ? wv16 : wo16;
    float4 a = *(const float4*)(in + i);
    float4 b = *(const float4*)(in + i + 4);
    half8 h;
    h[0] = (_Float16)a.x; h[1] = (_Float16)a.y; h[2] = (_Float16)a.z; h[3] = (_Float16)a.w;
    h[4] = (_Float16)b.x; h[5] = (_Float16)b.y; h[6] = (_Float16)b.z; h[7] = (_Float16)b.w;
    *(half8*)(out + i) = h;
}

// ---------------- GEMM body: C[m,n] = sum_k A[m,k]*W[n,k] + bias[n] ----------------
// VT=true: write output transposed per-head for attention V:
//   token row -> (b = row>>11, l = row&2047), col -> (h = col>>6, dh = col&63)
//   C[((b*16 + h)*64 + dh)*2048 + l]   (4 consecutive l per lane -> half4 store)
template <typename OutT, bool VT>
__device__ __forceinline__ void gemm_body(
    const _Float16* __restrict__ A,
    const _Float16* __restrict__ W,
    const float* __restrict__ bias,
    OutT* __restrict__ C,
    int N, int K, int bm, int bn,
    _Float16* As, _Float16* Bs)
{
    const int tid = threadIdx.x;
    const int wv = tid >> 6;
    const int lane = tid & 63;
    const int lr = lane & 15;
    const int lk = lane >> 4;
    const int wm = wv >> 1, wn = wv & 1;

    f32x4 acc[4][4] = {};

    for (int k0 = 0; k0 < K; k0 += 64) {
        __syncthreads();
#pragma unroll
        for (int i = 0; i < 4; ++i) {
            int chunk = i * 256 + tid;
            int row = chunk >> 3, c8 = chunk & 7;
            gld_lds16(A + (size_t)(bm * 128 + row) * K + k0 + c8 * 8, &As[chunk * 8]);
        }
#pragma unroll
        for (int i = 0; i < 4; ++i) {
            int chunk = i * 256 + tid;
            int row = chunk >> 3, c8 = chunk & 7;
            gld_lds16(W + (size_t)(bn * 128 + row) * K + k0 + c8 * 8, &Bs[chunk * 8]);
        }
        __syncthreads();

#pragma unroll
        for (int kk = 0; kk < 2; ++kk) {
            half8 a[4], b[4];
#pragma unroll
            for (int m = 0; m < 4; ++m)
                a[m] = *(const half8*)&As[(wm * 64 + m * 16 + lr) * 64 + kk * 32 + lk * 8];
#pragma unroll
            for (int n = 0; n < 4; ++n)
                b[n] = *(const half8*)&Bs[(wn * 64 + n * 16 + lr) * 64 + kk * 32 + lk * 8];
#pragma unroll
            for (int m = 0; m < 4; ++m)
#pragma unroll
                for (int n = 0; n < 4; ++n)
                    acc[m][n] = __builtin_amdgcn_mfma_f32_16x16x32_f16(a[m], b[n], acc[m][n], 0, 0, 0);
        }
    }

#pragma unroll
    for (int m = 0; m < 4; ++m) {
#pragma unroll
        for (int n = 0; n < 4; ++n) {
            int row0 = bm * 128 + wm * 64 + m * 16 + lk * 4;
            int col  = bn * 128 + wn * 64 + n * 16 + lr;
            float bb = bias[col];
            if (VT) {
                int b = row0 >> 11, l0 = row0 & 2047, h = col >> 6, dh = col & 63;
                half4 hv;
#pragma unroll
                for (int r = 0; r < 4; ++r) hv[r] = (_Float16)(acc[m][n][r] + bb);
                *(half4*)&C[(size_t)(((b * 16 + h) * 64 + dh)) * 2048 + l0] = hv;
            } else {
#pragma unroll
                for (int r = 0; r < 4; ++r) {
                    float v = acc[m][n][r] + bb;
                    C[(size_t)(row0 + r) * N + col] = (OutT)v;
                }
            }
        }
    }
}

template <typename OutT>
__global__ __launch_bounds__(256) void gemm_bt(
    const _Float16* __restrict__ A, const _Float16* __restrict__ W,
    const float* __restrict__ bias, OutT* __restrict__ C,
    int M, int N, int K)
{
    __shared__ _Float16 As[128 * 64];
    __shared__ _Float16 Bs[128 * 64];
    const int nbn = N >> 7;
    gemm_body<OutT, false>(A, W, bias, C, N, K, blockIdx.x / nbn, blockIdx.x % nbn, As, Bs);
}

// QKV fused: blockIdx.y in {0,1,2} selects which projection; V written transposed.
__global__ __launch_bounds__(256) void gemm_qkv(
    const _Float16* __restrict__ xq, const _Float16* __restrict__ xkv,
    const _Float16* __restrict__ wqp, const _Float16* __restrict__ wkp, const _Float16* __restrict__ wvp,
    const float* __restrict__ bq, const float* __restrict__ bk, const float* __restrict__ bvv,
    _Float16* __restrict__ Qb, _Float16* __restrict__ Kb, _Float16* __restrict__ VbT)
{
    __shared__ _Float16 As[128 * 64];
    __shared__ _Float16 Bs[128 * 64];
    const int z = blockIdx.y;
    const _Float16* A = (z == 0) ? xq : xkv;
    const _Float16* W = (z == 0) ? wqp : (z == 1) ? wkp : wvp;
    const float* bias = (z == 0) ? bq : (z == 1) ? bk : bvv;
    if (z == 2)
        gemm_body<_Float16, true>(A, W, bias, VbT, 1024, 1024, blockIdx.x >> 3, blockIdx.x & 7, As, Bs);
    else
        gemm_body<_Float16, false>(A, W, bias, (z == 0) ? Qb : Kb, 1024, 1024, blockIdx.x >> 3, blockIdx.x & 7, As, Bs);
}

// ---------------- Flash attention ----------------
// Q,K: (B*L, 1024) f16, head h at cols [h*64,+64). VT: [b][h][dh=64][l=2048] f16.
// O: (B*L, 1024) f16. grid (L/64, B*H), 4 waves, wave w owns 16 q-rows.
// Ks: [128 kv][64 d], chunk swizzle c8 ^= row&7 (both sides).
// Vs: [64 d][128 kv], chunk swizzle c16 ^= d&15 (both sides).
__global__ __launch_bounds__(256) void attn_fwd(
    const _Float16* __restrict__ Q,
    const _Float16* __restrict__ Kt,
    const _Float16* __restrict__ VT,
    _Float16* __restrict__ O)
{
    constexpr int KT = 128;
    constexpr int PSTR = KT + 8;
    __shared__ __align__(16) _Float16 Ks[KT * 64];
    __shared__ __align__(16) _Float16 Vs[64 * KT];
    __shared__ __align__(16) _Float16 Ps[4][16 * PSTR];

    const int tid = threadIdx.x;
    const int wv = tid >> 6;
    const int lane = tid & 63;
    const int lr = lane & 15;
    const int lk = lane >> 4;
    const int qb = blockIdx.x;
    const int bh = blockIdx.y;
    const size_t base = (size_t)(bh >> 4) * (2048 * 1024) + (size_t)(bh & 15) * 64;
    const size_t vtbase = (size_t)bh * (64 * 2048);  // bh = b*16+h matches VT layout

    half8 qf[2];
    {
        const _Float16* qp = Q + base + (size_t)(qb * 64 + wv * 16 + lr) * 1024 + lk * 8;
        qf[0] = *(const half8*)qp;
        qf[1] = *(const half8*)(qp + 32);
    }

    float mr[4], ls[4];
    f32x4 o[4] = {};
#pragma unroll
    for (int r = 0; r < 4; ++r) { mr[r] = -1e30f; ls[r] = 0.f; }

    for (int kt = 0; kt < 2048; kt += KT) {
        __syncthreads();  // prior-iter LDS reads done before overwrite
        // stage K tile [128][64], source-chunk XOR swizzled (dest lane-linear)
#pragma unroll
        for (int i = 0; i < 4; ++i) {
            int chunk = i * 256 + tid;
            int row = chunk >> 3, c8 = chunk & 7;
            int c8s = c8 ^ (row & 7);
            gld_lds16(Kt + base + (size_t)(kt + row) * 1024 + c8s * 8, &Ks[chunk * 8]);
        }
        // stage V^T tile [64][128], source-chunk XOR swizzled (dest lane-linear)
#pragma unroll
        for (int i = 0; i < 4; ++i) {
            int chunk = i * 256 + tid;
            int row = chunk >> 4, c16 = chunk & 15;       // row = d (0..63)
            int c16s = c16 ^ (row & 15);
            gld_lds16(VT + vtbase + (size_t)row * 2048 + kt + c16s * 8, &Vs[chunk * 8]);
        }
        __syncthreads();  // staging drained (compiler emits vmcnt(0) at barrier)

        // S = Q K^T  (S row q = lk*4+reg, col kv = n*16+lr)
        f32x4 s[8] = {};
#pragma unroll
        for (int kk = 0; kk < 2; ++kk) {
#pragma unroll
            for (int n = 0; n < 8; ++n) {
                int row = n * 16 + lr;
                half8 b = *(const half8*)&Ks[row * 64 + ((kk * 4 + lk) ^ (row & 7)) * 8];
                s[n] = __builtin_amdgcn_mfma_f32_16x16x32_f16(qf[kk], b, s[n], 0, 0, 0);
            }
        }
        // scale + row max (reduce over lr lanes only: q-row lives in (lk, reg))
        float tm[4];
#pragma unroll
        for (int r = 0; r < 4; ++r) tm[r] = -1e30f;
#pragma unroll
        for (int n = 0; n < 8; ++n)
#pragma unroll
            for (int r = 0; r < 4; ++r) {
                float v = s[n][r] * 0.125f;
                s[n][r] = v;
                tm[r] = fmaxf(tm[r], v);
            }
#pragma unroll
        for (int off = 1; off < 16; off <<= 1)
#pragma unroll
            for (int r = 0; r < 4; ++r)
                tm[r] = fmaxf(tm[r], __shfl_xor(tm[r], off));

        float al[4], rs[4];
#pragma unroll
        for (int r = 0; r < 4; ++r) {
            float mn = fmaxf(mr[r], tm[r]);
            al[r] = __expf(mr[r] - mn);
            mr[r] = mn;
            rs[r] = 0.f;
        }
        // P = exp(S - m) -> padded Ps (f16 round-trip for PV A-operand)
#pragma unroll
        for (int n = 0; n < 8; ++n)
#pragma unroll
            for (int r = 0; r < 4; ++r) {
                float p = __expf(s[n][r] - mr[r]);
                rs[r] += p;
                Ps[wv][(lk * 4 + r) * PSTR + n * 16 + lr] = (_Float16)p;
            }
#pragma unroll
        for (int off = 1; off < 16; off <<= 1)
#pragma unroll
            for (int r = 0; r < 4; ++r)
                rs[r] += __shfl_xor(rs[r], off);
#pragma unroll
        for (int r = 0; r < 4; ++r) ls[r] = ls[r] * al[r] + rs[r];
#pragma unroll
        for (int nd = 0; nd < 4; ++nd)
#pragma unroll
            for (int r = 0; r < 4; ++r) o[nd][r] *= al[r];

        // O += P * V : A-frag from Ps (wave-local), B-frag = VT rows (swizzled b128)
#pragma unroll
        for (int kk = 0; kk < 4; ++kk) {
            half8 pa = *(const half8*)&Ps[wv][lr * PSTR + kk * 32 + lk * 8];
#pragma unroll
            for (int nd = 0; nd < 4; ++nd) {
                int drow = nd * 16 + lr;
                half8 bv = *(const half8*)&Vs[drow * KT + (((kk * 4 + lk) ^ (drow & 15))) * 8];
                o[nd] = __builtin_amdgcn_mfma_f32_16x16x32_f16(pa, bv, o[nd], 0, 0, 0);
            }
        }
    }

#pragma unroll
    for (int nd = 0; nd < 4; ++nd) {
        int col = nd * 16 + lr;
#pragma unroll
        for (int r = 0; r < 4; ++r) {
            int qrow = qb * 64 + wv * 16 + lk * 4 + r;
            float val = o[nd][r] / ls[r];
            O[base + (size_t)qrow * 1024 + col] = (_Float16)val;
        }
    }
}

extern "C" void kernel_launch(void* const* d_in, const int* in_sizes, int n_in,
                              void* d_out, int out_size, void* d_ws, size_t ws_size,
                              hipStream_t stream) {
    const float* x_q  = (const float*)d_in[0];
    const float* x_kv = (const float*)d_in[1];
    const float* wq   = (const float*)d_in[2];
    const float* bq   = (const float*)d_in[3];
    const float* wk   = (const float*)d_in[4];
    const float* bk   = (const float*)d_in[5];
    const float* wvp  = (const float*)d_in[6];
    const float* bv   = (const float*)d_in[7];
    const float* wo   = (const float*)d_in[8];
    const float* bo   = (const float*)d_in[9];
    float* out = (float*)d_out;

    const size_t MX = (size_t)4096 * 1024;
    const size_t WX = (size_t)1024 * 1024;
    _Float16* ws    = (_Float16*)d_ws;
    _Float16* xq16  = ws;
    _Float16* xkv16 = xq16 + MX;
    _Float16* wq16  = xkv16 + MX;
    _Float16* wk16  = wq16 + WX;
    _Float16* wv16  = wk16 + WX;
    _Float16* wo16  = wv16 + WX;
    _Float16* Qb    = wo16 + WX;
    _Float16* Kb    = Qb + MX;
    _Float16* VbT   = Kb + MX;
    _Float16* AO    = VbT + MX;

    cvt_all<<<dim3(2048, 6), 256, 0, stream>>>(x_q, x_kv, wq, wk, wvp, wo,
                                               xq16, xkv16, wq16, wk16, wv16, wo16);

    gemm_qkv<<<dim3(256, 3), 256, 0, stream>>>(xq16, xkv16, wq16, wk16, wv16,
                                               bq, bk, bv, Qb, Kb, VbT);

    attn_fwd<<<dim3(32, 32), 256, 0, stream>>>(Qb, Kb, VbT, AO);

    gemm_bt<float><<<dim3(256), 256, 0, stream>>>(AO, wo16, bo, out, 4096, 1024, 1024);
}

// Round 6
// 165.597 us; speedup vs baseline: 1.8536x; 1.2140x over previous
//
#include <hip/hip_runtime.h>
#include <hip/hip_bf16.h>

typedef _Float16 __attribute__((ext_vector_type(8))) half8;
typedef _Float16 __attribute__((ext_vector_type(4))) half4;
typedef float __attribute__((ext_vector_type(4))) f32x4;

typedef __attribute__((address_space(1))) void gvoid_t;
typedef __attribute__((address_space(3))) void lvoid_t;

__device__ __forceinline__ void gld_lds16(const void* g, void* l) {
    __builtin_amdgcn_global_load_lds((const gvoid_t*)g, (lvoid_t*)l, 16, 0, 0);
}

// ---------------- f32 -> f16 convert, all 6 tensors in one launch ----------------
__global__ void cvt_all(const float* __restrict__ x_q, const float* __restrict__ x_kv,
                        const float* __restrict__ wq, const float* __restrict__ wk,
                        const float* __restrict__ wv, const float* __restrict__ wo,
                        _Float16* __restrict__ xq16, _Float16* __restrict__ xkv16,
                        _Float16* __restrict__ wq16, _Float16* __restrict__ wk16,
                        _Float16* __restrict__ wv16, _Float16* __restrict__ wo16)
{
    const int y = blockIdx.y;
    const int n = (y < 2) ? (4096 * 1024) : (1024 * 1024);
    int i = (blockIdx.x * 256 + threadIdx.x) * 8;
    if (i >= n) return;
    const float* in = (y == 0) ? x_q : (y == 1) ? x_kv : (y == 2) ? wq : (y == 3) ? wk : (y == 4) ? wv : wo;
    _Float16* out = (y == 0) ? xq16 : (y == 1) ? xkv16 : (y == 2) ? wq16 : (y == 3) ? wk16 : (y == 4) ? wv16 : wo16;
    float4 a = *(const float4*)(in + i);
    float4 b = *(const float4*)(in + i + 4);
    half8 h;
    h[0] = (_Float16)a.x; h[1] = (_Float16)a.y; h[2] = (_Float16)a.z; h[3] = (_Float16)a.w;
    h[4] = (_Float16)b.x; h[5] = (_Float16)b.y; h[6] = (_Float16)b.z; h[7] = (_Float16)b.w;
    *(half8*)(out + i) = h;
}

// ---------------- GEMM body: C[m,n] = (sum_k A[m,k]*W[n,k] + bias[n]) * osc ----------------
// VT=true: write output transposed per-head for attention V:
//   C[((b*16 + h)*64 + dh)*2048 + l]   (4 consecutive l per lane -> half4 store)
template <typename OutT, bool VT>
__device__ __forceinline__ void gemm_body(
    const _Float16* __restrict__ A,
    const _Float16* __restrict__ W,
    const float* __restrict__ bias,
    OutT* __restrict__ C,
    int N, int K, int bm, int bn, float osc,
    _Float16* As, _Float16* Bs)
{
    const int tid = threadIdx.x;
    const int wv = tid >> 6;
    const int lane = tid & 63;
    const int lr = lane & 15;
    const int lk = lane >> 4;
    const int wm = wv >> 1, wn = wv & 1;

    f32x4 acc[4][4] = {};

    for (int k0 = 0; k0 < K; k0 += 64) {
        __syncthreads();
#pragma unroll
        for (int i = 0; i < 4; ++i) {
            int chunk = i * 256 + tid;
            int row = chunk >> 3, c8 = chunk & 7;
            gld_lds16(A + (size_t)(bm * 128 + row) * K + k0 + c8 * 8, &As[chunk * 8]);
        }
#pragma unroll
        for (int i = 0; i < 4; ++i) {
            int chunk = i * 256 + tid;
            int row = chunk >> 3, c8 = chunk & 7;
            gld_lds16(W + (size_t)(bn * 128 + row) * K + k0 + c8 * 8, &Bs[chunk * 8]);
        }
        __syncthreads();

#pragma unroll
        for (int kk = 0; kk < 2; ++kk) {
            half8 a[4], b[4];
#pragma unroll
            for (int m = 0; m < 4; ++m)
                a[m] = *(const half8*)&As[(wm * 64 + m * 16 + lr) * 64 + kk * 32 + lk * 8];
#pragma unroll
            for (int n = 0; n < 4; ++n)
                b[n] = *(const half8*)&Bs[(wn * 64 + n * 16 + lr) * 64 + kk * 32 + lk * 8];
#pragma unroll
            for (int m = 0; m < 4; ++m)
#pragma unroll
                for (int n = 0; n < 4; ++n)
                    acc[m][n] = __builtin_amdgcn_mfma_f32_16x16x32_f16(a[m], b[n], acc[m][n], 0, 0, 0);
        }
    }

#pragma unroll
    for (int m = 0; m < 4; ++m) {
#pragma unroll
        for (int n = 0; n < 4; ++n) {
            int row0 = bm * 128 + wm * 64 + m * 16 + lk * 4;
            int col  = bn * 128 + wn * 64 + n * 16 + lr;
            float bb = bias[col];
            if (VT) {
                int b = row0 >> 11, l0 = row0 & 2047, h = col >> 6, dh = col & 63;
                half4 hv;
#pragma unroll
                for (int r = 0; r < 4; ++r) hv[r] = (_Float16)((acc[m][n][r] + bb) * osc);
                *(half4*)&C[(size_t)(((b * 16 + h) * 64 + dh)) * 2048 + l0] = hv;
            } else {
#pragma unroll
                for (int r = 0; r < 4; ++r) {
                    float v = (acc[m][n][r] + bb) * osc;
                    C[(size_t)(row0 + r) * N + col] = (OutT)v;
                }
            }
        }
    }
}

template <typename OutT>
__global__ __launch_bounds__(256) void gemm_bt(
    const _Float16* __restrict__ A, const _Float16* __restrict__ W,
    const float* __restrict__ bias, OutT* __restrict__ C,
    int M, int N, int K)
{
    __shared__ _Float16 As[128 * 64];
    __shared__ _Float16 Bs[128 * 64];
    const int nbn = N >> 7;
    gemm_body<OutT, false>(A, W, bias, C, N, K, blockIdx.x / nbn, blockIdx.x % nbn, 1.0f, As, Bs);
}

// QKV fused: blockIdx.y selects projection; Q pre-scaled by 1/8; V written transposed.
__global__ __launch_bounds__(256) void gemm_qkv(
    const _Float16* __restrict__ xq, const _Float16* __restrict__ xkv,
    const _Float16* __restrict__ wqp, const _Float16* __restrict__ wkp, const _Float16* __restrict__ wvp,
    const float* __restrict__ bq, const float* __restrict__ bk, const float* __restrict__ bvv,
    _Float16* __restrict__ Qb, _Float16* __restrict__ Kb, _Float16* __restrict__ VbT)
{
    __shared__ _Float16 As[128 * 64];
    __shared__ _Float16 Bs[128 * 64];
    const int z = blockIdx.y;
    const _Float16* A = (z == 0) ? xq : xkv;
    const _Float16* W = (z == 0) ? wqp : (z == 1) ? wkp : wvp;
    const float* bias = (z == 0) ? bq : (z == 1) ? bk : bvv;
    if (z == 2)
        gemm_body<_Float16, true>(A, W, bias, VbT, 1024, 1024, blockIdx.x >> 3, blockIdx.x & 7, 1.0f, As, Bs);
    else
        gemm_body<_Float16, false>(A, W, bias, (z == 0) ? Qb : Kb, 1024, 1024,
                                   blockIdx.x >> 3, blockIdx.x & 7, (z == 0) ? 0.125f : 1.0f, As, Bs);
}

// ---------------- Flash attention (swapped QK^T, in-register softmax) ----------------
// Q,K: (B*L, 1024) f16 (Q pre-scaled by 1/8). VT: [b][h][dh=64][l=2048] f16.
// grid (L/64, B*H), 4 waves, wave w owns 16 q-rows.
// S^T = mfma(K-frag, Q-frag): lane l holds S^T[kv=n*16+lk*4+r][q=lr] -> softmax in-register,
// P^T fragment (half4 per n) IS the B-operand of 16x16x16 PV MFMA. O^T = mfma(V^T, P^T).
__global__ __launch_bounds__(256) void attn_fwd(
    const _Float16* __restrict__ Q,
    const _Float16* __restrict__ Kt,
    const _Float16* __restrict__ VT,
    _Float16* __restrict__ O)
{
    constexpr int KT = 128;
    __shared__ __align__(16) _Float16 Ks[KT * 64];   // [kv][d], chunk swz c8 ^= kv&7
    __shared__ __align__(16) _Float16 Vs[64 * KT];   // [d][kv], chunk swz c16 ^= d&15

    const int tid = threadIdx.x;
    const int wv = tid >> 6;
    const int lane = tid & 63;
    const int lr = lane & 15;
    const int lk = lane >> 4;
    const int qb = blockIdx.x;
    const int bh = blockIdx.y;
    const size_t base = (size_t)(bh >> 4) * (2048 * 1024) + (size_t)(bh & 15) * 64;
    const size_t vtbase = (size_t)bh * (64 * 2048);

    half8 qf[2];
    {
        const _Float16* qp = Q + base + (size_t)(qb * 64 + wv * 16 + lr) * 1024 + lk * 8;
        qf[0] = *(const half8*)qp;
        qf[1] = *(const half8*)(qp + 32);
    }

    float mr = -1e30f, ls = 0.f;
    f32x4 o[4] = {};

    for (int kt = 0; kt < 2048; kt += KT) {
        __syncthreads();  // prior-iter LDS reads done before overwrite
#pragma unroll
        for (int i = 0; i < 4; ++i) {
            int chunk = i * 256 + tid;
            int row = chunk >> 3, c8 = chunk & 7;
            int c8s = c8 ^ (row & 7);
            gld_lds16(Kt + base + (size_t)(kt + row) * 1024 + c8s * 8, &Ks[chunk * 8]);
        }
#pragma unroll
        for (int i = 0; i < 4; ++i) {
            int chunk = i * 256 + tid;
            int row = chunk >> 4, c16 = chunk & 15;       // row = d (0..63)
            int c16s = c16 ^ (row & 15);
            gld_lds16(VT + vtbase + (size_t)row * 2048 + kt + c16s * 8, &Vs[chunk * 8]);
        }
        __syncthreads();  // staging drained

        // S^T = K Q^T (A = K-frag, B = Q-frag; both already in required layouts)
        f32x4 s[8] = {};
#pragma unroll
        for (int kk = 0; kk < 2; ++kk) {
#pragma unroll
            for (int n = 0; n < 8; ++n) {
                int row = n * 16 + lr;
                half8 a = *(const half8*)&Ks[row * 64 + ((kk * 4 + lk) ^ (row & 7)) * 8];
                s[n] = __builtin_amdgcn_mfma_f32_16x16x32_f16(a, qf[kk], s[n], 0, 0, 0);
            }
        }

        // in-register softmax: lane owns q=lr, 32 kv values; 4-lane group reduce
        float tm = -1e30f;
#pragma unroll
        for (int n = 0; n < 8; ++n)
#pragma unroll
            for (int r = 0; r < 4; ++r) tm = fmaxf(tm, s[n][r]);
        tm = fmaxf(tm, __shfl_xor(tm, 16));
        tm = fmaxf(tm, __shfl_xor(tm, 32));

        float mn = fmaxf(mr, tm);
        float al = __expf(mr - mn);
        mr = mn;
        float rs = 0.f;
        half4 pf[8];
#pragma unroll
        for (int n = 0; n < 8; ++n)
#pragma unroll
            for (int r = 0; r < 4; ++r) {
                float p = __expf(s[n][r] - mn);
                rs += p;
                pf[n][r] = (_Float16)p;
            }
        rs += __shfl_xor(rs, 16);
        rs += __shfl_xor(rs, 32);
        ls = ls * al + rs;
#pragma unroll
        for (int nd = 0; nd < 4; ++nd)
#pragma unroll
            for (int r = 0; r < 4; ++r) o[nd][r] *= al;

        // O^T += V^T · P^T  (K=16 MFMAs; P^T fragment is in-lane)
#pragma unroll
        for (int kvb = 0; kvb < 8; ++kvb) {
#pragma unroll
            for (int nd = 0; nd < 4; ++nd) {
                int drow = nd * 16 + lr;
                int c16 = (kvb << 1) | (lk >> 1);
                int idx = drow * 128 + ((c16 ^ (drow & 15)) << 3) + ((lk & 1) << 2);
                half4 va = *(const half4*)&Vs[idx];
                o[nd] = __builtin_amdgcn_mfma_f32_16x16x16f16(va, pf[kvb], o[nd], 0, 0, 0);
            }
        }
    }

    // O^T[d][q] per lane -> store: q = lr row, d = nd*16 + lk*4 + r (half4 per nd)
    const float inv = 1.0f / ls;
    const size_t orow = base + (size_t)(qb * 64 + wv * 16 + lr) * 1024;
#pragma unroll
    for (int nd = 0; nd < 4; ++nd) {
        half4 hv;
#pragma unroll
        for (int r = 0; r < 4; ++r) hv[r] = (_Float16)(o[nd][r] * inv);
        *(half4*)&O[orow + nd * 16 + lk * 4] = hv;
    }
}

extern "C" void kernel_launch(void* const* d_in, const int* in_sizes, int n_in,
                              void* d_out, int out_size, void* d_ws, size_t ws_size,
                              hipStream_t stream) {
    const float* x_q  = (const float*)d_in[0];
    const float* x_kv = (const float*)d_in[1];
    const float* wq   = (const float*)d_in[2];
    const float* bq   = (const float*)d_in[3];
    const float* wk   = (const float*)d_in[4];
    const float* bk   = (const float*)d_in[5];
    const float* wvp  = (const float*)d_in[6];
    const float* bv   = (const float*)d_in[7];
    const float* wo   = (const float*)d_in[8];
    const float* bo   = (const float*)d_in[9];
    float* out = (float*)d_out;

    const size_t MX = (size_t)4096 * 1024;
    const size_t WX = (size_t)1024 * 1024;
    _Float16* ws    = (_Float16*)d_ws;
    _Float16* xq16  = ws;
    _Float16* xkv16 = xq16 + MX;
    _Float16* wq16  = xkv16 + MX;
    _Float16* wk16  = wq16 + WX;
    _Float16* wv16  = wk16 + WX;
    _Float16* wo16  = wv16 + WX;
    _Float16* Qb    = wo16 + WX;
    _Float16* Kb    = Qb + MX;
    _Float16* VbT   = Kb + MX;
    _Float16* AO    = VbT + MX;

    cvt_all<<<dim3(2048, 6), 256, 0, stream>>>(x_q, x_kv, wq, wk, wvp, wo,
                                               xq16, xkv16, wq16, wk16, wv16, wo16);

    gemm_qkv<<<dim3(256, 3), 256, 0, stream>>>(xq16, xkv16, wq16, wk16, wv16,
                                               bq, bk, bv, Qb, Kb, VbT);

    attn_fwd<<<dim3(32, 32), 256, 0, stream>>>(Qb, Kb, VbT, AO);

    gemm_bt<float><<<dim3(256), 256, 0, stream>>>(AO, wo16, bo, out, 4096, 1024, 1024);
}

// Round 8
// 155.685 us; speedup vs baseline: 1.9716x; 1.0637x over previous
//
#include <hip/hip_runtime.h>
#include <hip/hip_bf16.h>

typedef _Float16 __attribute__((ext_vector_type(8))) half8;
typedef _Float16 __attribute__((ext_vector_type(4))) half4;
typedef __fp16 __attribute__((ext_vector_type(2))) fp16x2;
typedef __fp16 __attribute__((ext_vector_type(4))) fp16x4;
typedef float __attribute__((ext_vector_type(4))) f32x4;

typedef __attribute__((address_space(1))) void gvoid_t;
typedef __attribute__((address_space(3))) void lvoid_t;

__device__ __forceinline__ void gld_lds16(const void* g, void* l) {
    __builtin_amdgcn_global_load_lds((const gvoid_t*)g, (lvoid_t*)l, 16, 0, 0);
}

// ---------------- f32 -> f16 convert, all 6 tensors in one launch ----------------
__global__ void cvt_all(const float* __restrict__ x_q, const float* __restrict__ x_kv,
                        const float* __restrict__ wq, const float* __restrict__ wk,
                        const float* __restrict__ wv, const float* __restrict__ wo,
                        _Float16* __restrict__ xq16, _Float16* __restrict__ xkv16,
                        _Float16* __restrict__ wq16, _Float16* __restrict__ wk16,
                        _Float16* __restrict__ wv16, _Float16* __restrict__ wo16)
{
    const int y = blockIdx.y;
    const int n = (y < 2) ? (4096 * 1024) : (1024 * 1024);
    int i = (blockIdx.x * 256 + threadIdx.x) * 8;
    if (i >= n) return;
    const float* in = (y == 0) ? x_q : (y == 1) ? x_kv : (y == 2) ? wq : (y == 3) ? wk : (y == 4) ? wv : wo;
    _Float16* out = (y == 0) ? xq16 : (y == 1) ? xkv16 : (y == 2) ? wq16 : (y == 3) ? wk16 : (y == 4) ? wv16 : wo16;
    float4 a = *(const float4*)(in + i);
    float4 b = *(const float4*)(in + i + 4);
    half8 h;
    h[0] = (_Float16)a.x; h[1] = (_Float16)a.y; h[2] = (_Float16)a.z; h[3] = (_Float16)a.w;
    h[4] = (_Float16)b.x; h[5] = (_Float16)b.y; h[6] = (_Float16)b.z; h[7] = (_Float16)b.w;
    *(half8*)(out + i) = h;
}

// ---------------- GEMM body: C[m,n] = (sum_k A[m,k]*W[n,k] + bias[n]) * osc ----------------
// VT=true: write output transposed per-head for attention V:
//   C[((b*16 + h)*64 + dh)*2048 + l]   (4 consecutive l per lane -> half4 store)
template <typename OutT, bool VT>
__device__ __forceinline__ void gemm_body(
    const _Float16* __restrict__ A,
    const _Float16* __restrict__ W,
    const float* __restrict__ bias,
    OutT* __restrict__ C,
    int N, int K, int bm, int bn, float osc,
    _Float16* As, _Float16* Bs)
{
    const int tid = threadIdx.x;
    const int wv = tid >> 6;
    const int lane = tid & 63;
    const int lr = lane & 15;
    const int lk = lane >> 4;
    const int wm = wv >> 1, wn = wv & 1;

    f32x4 acc[4][4] = {};

    for (int k0 = 0; k0 < K; k0 += 64) {
        __syncthreads();
#pragma unroll
        for (int i = 0; i < 4; ++i) {
            int chunk = i * 256 + tid;
            int row = chunk >> 3, c8 = chunk & 7;
            gld_lds16(A + (size_t)(bm * 128 + row) * K + k0 + c8 * 8, &As[chunk * 8]);
        }
#pragma unroll
        for (int i = 0; i < 4; ++i) {
            int chunk = i * 256 + tid;
            int row = chunk >> 3, c8 = chunk & 7;
            gld_lds16(W + (size_t)(bn * 128 + row) * K + k0 + c8 * 8, &Bs[chunk * 8]);
        }
        __syncthreads();

#pragma unroll
        for (int kk = 0; kk < 2; ++kk) {
            half8 a[4], b[4];
#pragma unroll
            for (int m = 0; m < 4; ++m)
                a[m] = *(const half8*)&As[(wm * 64 + m * 16 + lr) * 64 + kk * 32 + lk * 8];
#pragma unroll
            for (int n = 0; n < 4; ++n)
                b[n] = *(const half8*)&Bs[(wn * 64 + n * 16 + lr) * 64 + kk * 32 + lk * 8];
#pragma unroll
            for (int m = 0; m < 4; ++m)
#pragma unroll
                for (int n = 0; n < 4; ++n)
                    acc[m][n] = __builtin_amdgcn_mfma_f32_16x16x32_f16(a[m], b[n], acc[m][n], 0, 0, 0);
        }
    }

#pragma unroll
    for (int m = 0; m < 4; ++m) {
#pragma unroll
        for (int n = 0; n < 4; ++n) {
            int row0 = bm * 128 + wm * 64 + m * 16 + lk * 4;
            int col  = bn * 128 + wn * 64 + n * 16 + lr;
            float bb = bias[col];
            if (VT) {
                int b = row0 >> 11, l0 = row0 & 2047, h = col >> 6, dh = col & 63;
                half4 hv;
#pragma unroll
                for (int r = 0; r < 4; ++r) hv[r] = (_Float16)((acc[m][n][r] + bb) * osc);
                *(half4*)&C[(size_t)(((b * 16 + h) * 64 + dh)) * 2048 + l0] = hv;
            } else {
#pragma unroll
                for (int r = 0; r < 4; ++r) {
                    float v = (acc[m][n][r] + bb) * osc;
                    C[(size_t)(row0 + r) * N + col] = (OutT)v;
                }
            }
        }
    }
}

template <typename OutT>
__global__ __launch_bounds__(256) void gemm_bt(
    const _Float16* __restrict__ A, const _Float16* __restrict__ W,
    const float* __restrict__ bias, OutT* __restrict__ C,
    int M, int N, int K)
{
    __shared__ _Float16 As[128 * 64];
    __shared__ _Float16 Bs[128 * 64];
    const int nbn = N >> 7;
    gemm_body<OutT, false>(A, W, bias, C, N, K, blockIdx.x / nbn, blockIdx.x % nbn, 1.0f, As, Bs);
}

// QKV fused: blockIdx.y selects projection; Q pre-scaled by log2(e)/8; V written transposed.
__global__ __launch_bounds__(256) void gemm_qkv(
    const _Float16* __restrict__ xq, const _Float16* __restrict__ xkv,
    const _Float16* __restrict__ wqp, const _Float16* __restrict__ wkp, const _Float16* __restrict__ wvp,
    const float* __restrict__ bq, const float* __restrict__ bk, const float* __restrict__ bvv,
    _Float16* __restrict__ Qb, _Float16* __restrict__ Kb, _Float16* __restrict__ VbT)
{
    __shared__ _Float16 As[128 * 64];
    __shared__ _Float16 Bs[128 * 64];
    const int z = blockIdx.y;
    const _Float16* A = (z == 0) ? xq : xkv;
    const _Float16* W = (z == 0) ? wqp : (z == 1) ? wkp : wvp;
    const float* bias = (z == 0) ? bq : (z == 1) ? bk : bvv;
    if (z == 2)
        gemm_body<_Float16, true>(A, W, bias, VbT, 1024, 1024, blockIdx.x >> 3, blockIdx.x & 7, 1.0f, As, Bs);
    else
        gemm_body<_Float16, false>(A, W, bias, (z == 0) ? Qb : Kb, 1024, 1024,
                                   blockIdx.x >> 3, blockIdx.x & 7,
                                   (z == 0) ? (0.125f * 1.44269504088896f) : 1.0f, As, Bs);
}

// ---------------- Flash attention (swapped QK^T, in-register softmax, exp2 domain) ----------------
// Q,K: (B*L, 1024) f16 (Q pre-scaled by log2e/8). VT: [b][h][dh=64][l=2048] f16.
// grid (L/64, B*H), 4 waves, wave w owns 16 q-rows.
// S^T = mfma(K-frag, Q-frag): lane l holds S^T[kv=n*16+lk*4+r][q=lr]; softmax in-register;
// P^T fragment IS the B-operand of 16x16x16 PV MFMA. O^T = mfma(V^T, P^T).
// All LDS read base addresses are kt-invariant -> hoisted; inner reads use offset imms.
__global__ __launch_bounds__(256, 4) void attn_fwd(
    const _Float16* __restrict__ Q,
    const _Float16* __restrict__ Kt,
    const _Float16* __restrict__ VT,
    _Float16* __restrict__ O)
{
    constexpr int KT = 128;
    __shared__ __align__(16) _Float16 Ks[KT * 64];   // [kv][d], chunk swz c8 ^= kv&7
    __shared__ __align__(16) _Float16 Vs[64 * KT];   // [d][kv], chunk swz c16 ^= d&15

    const int tid = threadIdx.x;
    const int wv = tid >> 6;
    const int lane = tid & 63;
    const int lr = lane & 15;
    const int lk = lane >> 4;
    const int qb = blockIdx.x;
    const int bh = blockIdx.y;
    const size_t base = (size_t)(bh >> 4) * (2048 * 1024) + (size_t)(bh & 15) * 64;
    const size_t vtbase = (size_t)bh * (64 * 2048);

    half8 qf[2];
    {
        const _Float16* qp = Q + base + (size_t)(qb * 64 + wv * 16 + lr) * 1024 + lk * 8;
        qf[0] = *(const half8*)qp;
        qf[1] = *(const half8*)(qp + 32);
    }

    // hoisted, kt-invariant LDS read bases
    const _Float16* kb0 = &Ks[lr * 64 + ((lk     ^ (lr & 7)) << 3)];   // + n*1024
    const _Float16* kb1 = &Ks[lr * 64 + (((4|lk) ^ (lr & 7)) << 3)];   // + n*1024
    const _Float16* vb[8];
#pragma unroll
    for (int kvb = 0; kvb < 8; ++kvb)
        vb[kvb] = &Vs[lr * 128 + ((((kvb << 1) | (lk >> 1)) ^ lr) << 3) + ((lk & 1) << 2)];  // + nd*2048

    float mr = -1e30f, ls = 0.f;
    f32x4 o[4] = {};

    for (int kt = 0; kt < 2048; kt += KT) {
        __syncthreads();  // prior-iter LDS reads done before overwrite
#pragma unroll
        for (int i = 0; i < 4; ++i) {
            int chunk = i * 256 + tid;
            int row = chunk >> 3, c8 = chunk & 7;
            int c8s = c8 ^ (row & 7);
            gld_lds16(Kt + base + (size_t)(kt + row) * 1024 + c8s * 8, &Ks[chunk * 8]);
        }
#pragma unroll
        for (int i = 0; i < 4; ++i) {
            int chunk = i * 256 + tid;
            int row = chunk >> 4, c16 = chunk & 15;       // row = d (0..63)
            int c16s = c16 ^ (row & 15);
            gld_lds16(VT + vtbase + (size_t)row * 2048 + kt + c16s * 8, &Vs[chunk * 8]);
        }
        __syncthreads();  // staging drained

        // S^T = K Q^T (A = K-frag, B = Q-frag)
        f32x4 s[8] = {};
#pragma unroll
        for (int n = 0; n < 8; ++n) {
            half8 a0 = *(const half8*)(kb0 + n * 1024);
            s[n] = __builtin_amdgcn_mfma_f32_16x16x32_f16(a0, qf[0], s[n], 0, 0, 0);
        }
#pragma unroll
        for (int n = 0; n < 8; ++n) {
            half8 a1 = *(const half8*)(kb1 + n * 1024);
            s[n] = __builtin_amdgcn_mfma_f32_16x16x32_f16(a1, qf[1], s[n], 0, 0, 0);
        }

        // in-register softmax (exp2 domain): lane owns q=lr, 32 kv values
        float tm = -1e30f;
#pragma unroll
        for (int n = 0; n < 8; ++n)
#pragma unroll
            for (int r = 0; r < 4; ++r) tm = fmaxf(tm, s[n][r]);
        tm = fmaxf(tm, __shfl_xor(tm, 16));
        tm = fmaxf(tm, __shfl_xor(tm, 32));

        float mn = fmaxf(mr, tm);
        float al = __builtin_amdgcn_exp2f(mr - mn);
        mr = mn;
        float rs = 0.f;
        half4 pf[8];
#pragma unroll
        for (int n = 0; n < 8; ++n) {
            float p0 = __builtin_amdgcn_exp2f(s[n][0] - mn);
            float p1 = __builtin_amdgcn_exp2f(s[n][1] - mn);
            float p2 = __builtin_amdgcn_exp2f(s[n][2] - mn);
            float p3 = __builtin_amdgcn_exp2f(s[n][3] - mn);
            rs += (p0 + p1) + (p2 + p3);
            fp16x2 lo = __builtin_amdgcn_cvt_pkrtz(p0, p1);
            fp16x2 hi = __builtin_amdgcn_cvt_pkrtz(p2, p3);
            fp16x4 pv4 = __builtin_shufflevector(lo, hi, 0, 1, 2, 3);
            pf[n] = __builtin_bit_cast(half4, pv4);
        }
        rs += __shfl_xor(rs, 16);
        rs += __shfl_xor(rs, 32);
        ls = ls * al + rs;
#pragma unroll
        for (int nd = 0; nd < 4; ++nd)
#pragma unroll
            for (int r = 0; r < 4; ++r) o[nd][r] *= al;

        // O^T += V^T · P^T  (K=16 MFMAs; P^T fragment is in-lane)
#pragma unroll
        for (int kvb = 0; kvb < 8; ++kvb) {
#pragma unroll
            for (int nd = 0; nd < 4; ++nd) {
                half4 va = *(const half4*)(vb[kvb] + nd * 2048);
                o[nd] = __builtin_amdgcn_mfma_f32_16x16x16f16(va, pf[kvb], o[nd], 0, 0, 0);
            }
        }
    }

    // O^T[d][q] per lane -> store: q = lr row, d = nd*16 + lk*4 + r (half4 per nd)
    const float inv = 1.0f / ls;
    const size_t orow = base + (size_t)(qb * 64 + wv * 16 + lr) * 1024;
#pragma unroll
    for (int nd = 0; nd < 4; ++nd) {
        half4 hv;
#pragma unroll
        for (int r = 0; r < 4; ++r) hv[r] = (_Float16)(o[nd][r] * inv);
        *(half4*)&O[orow + nd * 16 + lk * 4] = hv;
    }
}

extern "C" void kernel_launch(void* const* d_in, const int* in_sizes, int n_in,
                              void* d_out, int out_size, void* d_ws, size_t ws_size,
                              hipStream_t stream) {
    const float* x_q  = (const float*)d_in[0];
    const float* x_kv = (const float*)d_in[1];
    const float* wq   = (const float*)d_in[2];
    const float* bq   = (const float*)d_in[3];
    const float* wk   = (const float*)d_in[4];
    const float* bk   = (const float*)d_in[5];
    const float* wvp  = (const float*)d_in[6];
    const float* bv   = (const float*)d_in[7];
    const float* wo   = (const float*)d_in[8];
    const float* bo   = (const float*)d_in[9];
    float* out = (float*)d_out;

    const size_t MX = (size_t)4096 * 1024;
    const size_t WX = (size_t)1024 * 1024;
    _Float16* ws    = (_Float16*)d_ws;
    _Float16* xq16  = ws;
    _Float16* xkv16 = xq16 + MX;
    _Float16* wq16  = xkv16 + MX;
    _Float16* wk16  = wq16 + WX;
    _Float16* wv16  = wk16 + WX;
    _Float16* wo16  = wv16 + WX;
    _Float16* Qb    = wo16 + WX;
    _Float16* Kb    = Qb + MX;
    _Float16* VbT   = Kb + MX;
    _Float16* AO    = VbT + MX;

    cvt_all<<<dim3(2048, 6), 256, 0, stream>>>(x_q, x_kv, wq, wk, wvp, wo,
                                               xq16, xkv16, wq16, wk16, wv16, wo16);

    gemm_qkv<<<dim3(256, 3), 256, 0, stream>>>(xq16, xkv16, wq16, wk16, wv16,
                                               bq, bk, bv, Qb, Kb, VbT);

    attn_fwd<<<dim3(32, 32), 256, 0, stream>>>(Qb, Kb, VbT, AO);

    gemm_bt<float><<<dim3(256), 256, 0, stream>>>(AO, wo16, bo, out, 4096, 1024, 1024);
}

// Round 9
// 140.999 us; speedup vs baseline: 2.1769x; 1.1042x over previous
//
#include <hip/hip_runtime.h>
#include <hip/hip_bf16.h>

typedef _Float16 __attribute__((ext_vector_type(8))) half8;
typedef _Float16 __attribute__((ext_vector_type(4))) half4;
typedef __fp16 __attribute__((ext_vector_type(2))) fp16x2;
typedef __fp16 __attribute__((ext_vector_type(4))) fp16x4;
typedef float __attribute__((ext_vector_type(4))) f32x4;

typedef __attribute__((address_space(1))) void gvoid_t;
typedef __attribute__((address_space(3))) void lvoid_t;

__device__ __forceinline__ void gld_lds16(const void* g, void* l) {
    __builtin_amdgcn_global_load_lds((const gvoid_t*)g, (lvoid_t*)l, 16, 0, 0);
}

// ---------------- f32 -> f16 convert, all 6 tensors in one launch ----------------
__global__ void cvt_all(const float* __restrict__ x_q, const float* __restrict__ x_kv,
                        const float* __restrict__ wq, const float* __restrict__ wk,
                        const float* __restrict__ wv, const float* __restrict__ wo,
                        _Float16* __restrict__ xq16, _Float16* __restrict__ xkv16,
                        _Float16* __restrict__ wq16, _Float16* __restrict__ wk16,
                        _Float16* __restrict__ wv16, _Float16* __restrict__ wo16)
{
    const int y = blockIdx.y;
    const int n = (y < 2) ? (4096 * 1024) : (1024 * 1024);
    int i = (blockIdx.x * 256 + threadIdx.x) * 8;
    if (i >= n) return;
    const float* in = (y == 0) ? x_q : (y == 1) ? x_kv : (y == 2) ? wq : (y == 3) ? wk : (y == 4) ? wv : wo;
    _Float16* out = (y == 0) ? xq16 : (y == 1) ? xkv16 : (y == 2) ? wq16 : (y == 3) ? wk16 : (y == 4) ? wv16 : wo16;
    float4 a = *(const float4*)(in + i);
    float4 b = *(const float4*)(in + i + 4);
    half8 h;
    h[0] = (_Float16)a.x; h[1] = (_Float16)a.y; h[2] = (_Float16)a.z; h[3] = (_Float16)a.w;
    h[4] = (_Float16)b.x; h[5] = (_Float16)b.y; h[6] = (_Float16)b.z; h[7] = (_Float16)b.w;
    *(half8*)(out + i) = h;
}

// ---------------- GEMM body: C[m,n] = (sum_k A[m,k]*W[n,k] + bias[n]) * osc ----------------
// Tile: 64 (M) x 128 (N), BK=64. 4 waves; wave (wm=wv>>1, wn=wv&1) owns 32x64.
// VT=true: write output transposed per-head for attention V:
//   C[((b*16 + h)*64 + dh)*2048 + l]   (4 consecutive l per lane -> half4 store)
template <typename OutT, bool VT>
__device__ __forceinline__ void gemm_body(
    const _Float16* __restrict__ A,
    const _Float16* __restrict__ W,
    const float* __restrict__ bias,
    OutT* __restrict__ C,
    int N, int K, int bm, int bn, float osc,
    _Float16* As, _Float16* Bs)
{
    const int tid = threadIdx.x;
    const int wv = tid >> 6;
    const int lane = tid & 63;
    const int lr = lane & 15;
    const int lk = lane >> 4;
    const int wm = wv >> 1, wn = wv & 1;

    f32x4 acc[2][4] = {};

    for (int k0 = 0; k0 < K; k0 += 64) {
        __syncthreads();
#pragma unroll
        for (int i = 0; i < 2; ++i) {
            int chunk = i * 256 + tid;              // 0..511: A tile 64x64
            int row = chunk >> 3, c8 = chunk & 7;
            gld_lds16(A + (size_t)(bm * 64 + row) * K + k0 + c8 * 8, &As[chunk * 8]);
        }
#pragma unroll
        for (int i = 0; i < 4; ++i) {
            int chunk = i * 256 + tid;              // 0..1023: B tile 128x64
            int row = chunk >> 3, c8 = chunk & 7;
            gld_lds16(W + (size_t)(bn * 128 + row) * K + k0 + c8 * 8, &Bs[chunk * 8]);
        }
        __syncthreads();

#pragma unroll
        for (int kk = 0; kk < 2; ++kk) {
            half8 a[2], b[4];
#pragma unroll
            for (int m = 0; m < 2; ++m)
                a[m] = *(const half8*)&As[(wm * 32 + m * 16 + lr) * 64 + kk * 32 + lk * 8];
#pragma unroll
            for (int n = 0; n < 4; ++n)
                b[n] = *(const half8*)&Bs[(wn * 64 + n * 16 + lr) * 64 + kk * 32 + lk * 8];
#pragma unroll
            for (int m = 0; m < 2; ++m)
#pragma unroll
                for (int n = 0; n < 4; ++n)
                    acc[m][n] = __builtin_amdgcn_mfma_f32_16x16x32_f16(a[m], b[n], acc[m][n], 0, 0, 0);
        }
    }

#pragma unroll
    for (int m = 0; m < 2; ++m) {
#pragma unroll
        for (int n = 0; n < 4; ++n) {
            int row0 = bm * 64 + wm * 32 + m * 16 + lk * 4;
            int col  = bn * 128 + wn * 64 + n * 16 + lr;
            float bb = bias[col];
            if (VT) {
                int b = row0 >> 11, l0 = row0 & 2047, h = col >> 6, dh = col & 63;
                half4 hv;
#pragma unroll
                for (int r = 0; r < 4; ++r) hv[r] = (_Float16)((acc[m][n][r] + bb) * osc);
                *(half4*)&C[(size_t)(((b * 16 + h) * 64 + dh)) * 2048 + l0] = hv;
            } else {
#pragma unroll
                for (int r = 0; r < 4; ++r) {
                    float v = (acc[m][n][r] + bb) * osc;
                    C[(size_t)(row0 + r) * N + col] = (OutT)v;
                }
            }
        }
    }
}

template <typename OutT>
__global__ __launch_bounds__(256) void gemm_bt(
    const _Float16* __restrict__ A, const _Float16* __restrict__ W,
    const float* __restrict__ bias, OutT* __restrict__ C,
    int M, int N, int K)
{
    __shared__ _Float16 As[64 * 64];
    __shared__ _Float16 Bs[128 * 64];
    const int nbn = N >> 7;
    gemm_body<OutT, false>(A, W, bias, C, N, K, blockIdx.x / nbn, blockIdx.x % nbn, 1.0f, As, Bs);
}

// QKV fused: blockIdx.y selects projection; Q pre-scaled by log2(e)/8; V written transposed.
__global__ __launch_bounds__(256) void gemm_qkv(
    const _Float16* __restrict__ xq, const _Float16* __restrict__ xkv,
    const _Float16* __restrict__ wqp, const _Float16* __restrict__ wkp, const _Float16* __restrict__ wvp,
    const float* __restrict__ bq, const float* __restrict__ bk, const float* __restrict__ bvv,
    _Float16* __restrict__ Qb, _Float16* __restrict__ Kb, _Float16* __restrict__ VbT)
{
    __shared__ _Float16 As[64 * 64];
    __shared__ _Float16 Bs[128 * 64];
    const int z = blockIdx.y;
    const _Float16* A = (z == 0) ? xq : xkv;
    const _Float16* W = (z == 0) ? wqp : (z == 1) ? wkp : wvp;
    const float* bias = (z == 0) ? bq : (z == 1) ? bk : bvv;
    const int bm = blockIdx.x >> 3, bn = blockIdx.x & 7;
    if (z == 2)
        gemm_body<_Float16, true>(A, W, bias, VbT, 1024, 1024, bm, bn, 1.0f, As, Bs);
    else
        gemm_body<_Float16, false>(A, W, bias, (z == 0) ? Qb : Kb, 1024, 1024, bm, bn,
                                   (z == 0) ? (0.125f * 1.44269504088896f) : 1.0f, As, Bs);
}

// ---------------- Flash attention (swapped QK^T, in-register softmax, exp2 domain) ----------------
// Q,K: (B*L, 1024) f16 (Q pre-scaled by log2e/8). VT: [b][h][dh=64][l=2048] f16.
// grid (L/128, B*H), 8 waves (512 thr); wave w owns 16 q-rows of the block's 128.
// S^T = mfma(K-frag, Q-frag): lane l holds S^T[kv=n*16+lk*4+r][q=lr]; softmax in-register;
// P^T fragment IS the B-operand of 16x16x16 PV MFMA. O^T = mfma(V^T, P^T).
// defer-max: skip rescale while per-tile max within 8 (log2 domain) of running max.
__global__ __launch_bounds__(512, 4) void attn_fwd(
    const _Float16* __restrict__ Q,
    const _Float16* __restrict__ Kt,
    const _Float16* __restrict__ VT,
    _Float16* __restrict__ O)
{
    constexpr int KT = 128;
    __shared__ __align__(16) _Float16 Ks[KT * 64];   // [kv][d], chunk swz c8 ^= kv&7
    __shared__ __align__(16) _Float16 Vs[64 * KT];   // [d][kv], chunk swz c16 ^= d&15

    const int tid = threadIdx.x;
    const int wv = tid >> 6;
    const int lane = tid & 63;
    const int lr = lane & 15;
    const int lk = lane >> 4;
    const int qb = blockIdx.x;
    const int bh = blockIdx.y;
    const size_t base = (size_t)(bh >> 4) * (2048 * 1024) + (size_t)(bh & 15) * 64;
    const size_t vtbase = (size_t)bh * (64 * 2048);

    half8 qf[2];
    {
        const _Float16* qp = Q + base + (size_t)(qb * 128 + wv * 16 + lr) * 1024 + lk * 8;
        qf[0] = *(const half8*)qp;
        qf[1] = *(const half8*)(qp + 32);
    }

    // hoisted, kt-invariant LDS read bases
    const _Float16* kb0 = &Ks[lr * 64 + ((lk     ^ (lr & 7)) << 3)];   // + n*1024
    const _Float16* kb1 = &Ks[lr * 64 + (((4|lk) ^ (lr & 7)) << 3)];   // + n*1024
    const _Float16* vb[8];
#pragma unroll
    for (int kvb = 0; kvb < 8; ++kvb)
        vb[kvb] = &Vs[lr * 128 + ((((kvb << 1) | (lk >> 1)) ^ lr) << 3) + ((lk & 1) << 2)];  // + nd*2048

    float mr = -1e30f, ls = 0.f;
    f32x4 o[4] = {};

    for (int kt = 0; kt < 2048; kt += KT) {
        __syncthreads();  // prior-iter LDS reads done before overwrite
#pragma unroll
        for (int i = 0; i < 2; ++i) {
            int chunk = i * 512 + tid;              // 0..1023: K tile 128x64
            int row = chunk >> 3, c8 = chunk & 7;
            int c8s = c8 ^ (row & 7);
            gld_lds16(Kt + base + (size_t)(kt + row) * 1024 + c8s * 8, &Ks[chunk * 8]);
        }
#pragma unroll
        for (int i = 0; i < 2; ++i) {
            int chunk = i * 512 + tid;              // 0..1023: V^T tile 64x128
            int row = chunk >> 4, c16 = chunk & 15; // row = d (0..63)
            int c16s = c16 ^ (row & 15);
            gld_lds16(VT + vtbase + (size_t)row * 2048 + kt + c16s * 8, &Vs[chunk * 8]);
        }
        __syncthreads();  // staging drained

        // S^T = K Q^T (A = K-frag, B = Q-frag)
        f32x4 s[8] = {};
#pragma unroll
        for (int n = 0; n < 8; ++n) {
            half8 a0 = *(const half8*)(kb0 + n * 1024);
            s[n] = __builtin_amdgcn_mfma_f32_16x16x32_f16(a0, qf[0], s[n], 0, 0, 0);
        }
#pragma unroll
        for (int n = 0; n < 8; ++n) {
            half8 a1 = *(const half8*)(kb1 + n * 1024);
            s[n] = __builtin_amdgcn_mfma_f32_16x16x32_f16(a1, qf[1], s[n], 0, 0, 0);
        }

        // in-register softmax (exp2 domain): lane owns q=lr, 32 kv values
        float tm = -1e30f;
#pragma unroll
        for (int n = 0; n < 8; ++n)
#pragma unroll
            for (int r = 0; r < 4; ++r) tm = fmaxf(tm, s[n][r]);
        tm = fmaxf(tm, __shfl_xor(tm, 16));
        tm = fmaxf(tm, __shfl_xor(tm, 32));

        // defer-max: only rescale when tile max exceeds running max by >8 (P <= 2^8)
        if (!__all(tm <= mr + 8.0f)) {
            float mn = fmaxf(mr, tm);
            float al = __builtin_amdgcn_exp2f(mr - mn);
            mr = mn;
            ls *= al;
#pragma unroll
            for (int nd = 0; nd < 4; ++nd)
#pragma unroll
                for (int r = 0; r < 4; ++r) o[nd][r] *= al;
        }

        float rs = 0.f;
        half4 pf[8];
#pragma unroll
        for (int n = 0; n < 8; ++n) {
            float p0 = __builtin_amdgcn_exp2f(s[n][0] - mr);
            float p1 = __builtin_amdgcn_exp2f(s[n][1] - mr);
            float p2 = __builtin_amdgcn_exp2f(s[n][2] - mr);
            float p3 = __builtin_amdgcn_exp2f(s[n][3] - mr);
            rs += (p0 + p1) + (p2 + p3);
            fp16x2 lo = __builtin_amdgcn_cvt_pkrtz(p0, p1);
            fp16x2 hi = __builtin_amdgcn_cvt_pkrtz(p2, p3);
            fp16x4 pv4 = __builtin_shufflevector(lo, hi, 0, 1, 2, 3);
            pf[n] = __builtin_bit_cast(half4, pv4);
        }
        rs += __shfl_xor(rs, 16);
        rs += __shfl_xor(rs, 32);
        ls += rs;

        // O^T += V^T · P^T  (K=16 MFMAs; P^T fragment is in-lane)
#pragma unroll
        for (int kvb = 0; kvb < 8; ++kvb) {
#pragma unroll
            for (int nd = 0; nd < 4; ++nd) {
                half4 va = *(const half4*)(vb[kvb] + nd * 2048);
                o[nd] = __builtin_amdgcn_mfma_f32_16x16x16f16(va, pf[kvb], o[nd], 0, 0, 0);
            }
        }
    }

    // O^T[d][q] per lane -> store: q = lr row, d = nd*16 + lk*4 + r (half4 per nd)
    const float inv = 1.0f / ls;
    const size_t orow = base + (size_t)(qb * 128 + wv * 16 + lr) * 1024;
#pragma unroll
    for (int nd = 0; nd < 4; ++nd) {
        half4 hv;
#pragma unroll
        for (int r = 0; r < 4; ++r) hv[r] = (_Float16)(o[nd][r] * inv);
        *(half4*)&O[orow + nd * 16 + lk * 4] = hv;
    }
}

extern "C" void kernel_launch(void* const* d_in, const int* in_sizes, int n_in,
                              void* d_out, int out_size, void* d_ws, size_t ws_size,
                              hipStream_t stream) {
    const float* x_q  = (const float*)d_in[0];
    const float* x_kv = (const float*)d_in[1];
    const float* wq   = (const float*)d_in[2];
    const float* bq   = (const float*)d_in[3];
    const float* wk   = (const float*)d_in[4];
    const float* bk   = (const float*)d_in[5];
    const float* wvp  = (const float*)d_in[6];
    const float* bv   = (const float*)d_in[7];
    const float* wo   = (const float*)d_in[8];
    const float* bo   = (const float*)d_in[9];
    float* out = (float*)d_out;

    const size_t MX = (size_t)4096 * 1024;
    const size_t WX = (size_t)1024 * 1024;
    _Float16* ws    = (_Float16*)d_ws;
    _Float16* xq16  = ws;
    _Float16* xkv16 = xq16 + MX;
    _Float16* wq16  = xkv16 + MX;
    _Float16* wk16  = wq16 + WX;
    _Float16* wv16  = wk16 + WX;
    _Float16* wo16  = wv16 + WX;
    _Float16* Qb    = wo16 + WX;
    _Float16* Kb    = Qb + MX;
    _Float16* VbT   = Kb + MX;
    _Float16* AO    = VbT + MX;

    cvt_all<<<dim3(2048, 6), 256, 0, stream>>>(x_q, x_kv, wq, wk, wvp, wo,
                                               xq16, xkv16, wq16, wk16, wv16, wo16);

    gemm_qkv<<<dim3(512, 3), 256, 0, stream>>>(xq16, xkv16, wq16, wk16, wv16,
                                               bq, bk, bv, Qb, Kb, VbT);

    attn_fwd<<<dim3(16, 32), 512, 0, stream>>>(Qb, Kb, VbT, AO);

    gemm_bt<float><<<dim3(512), 256, 0, stream>>>(AO, wo16, bo, out, 4096, 1024, 1024);
}

// Round 10
// 138.879 us; speedup vs baseline: 2.2102x; 1.0153x over previous
//
#include <hip/hip_runtime.h>
#include <hip/hip_bf16.h>

typedef _Float16 __attribute__((ext_vector_type(8))) half8;
typedef _Float16 __attribute__((ext_vector_type(4))) half4;
typedef __fp16 __attribute__((ext_vector_type(2))) fp16x2;
typedef __fp16 __attribute__((ext_vector_type(4))) fp16x4;
typedef float __attribute__((ext_vector_type(4))) f32x4;

typedef __attribute__((address_space(1))) void gvoid_t;
typedef __attribute__((address_space(3))) void lvoid_t;

__device__ __forceinline__ void gld_lds16(const void* g, void* l) {
    __builtin_amdgcn_global_load_lds((const gvoid_t*)g, (lvoid_t*)l, 16, 0, 0);
}

// ---------------- f32 -> f16 convert, all 6 tensors in one launch ----------------
__global__ void cvt_all(const float* __restrict__ x_q, const float* __restrict__ x_kv,
                        const float* __restrict__ wq, const float* __restrict__ wk,
                        const float* __restrict__ wv, const float* __restrict__ wo,
                        _Float16* __restrict__ xq16, _Float16* __restrict__ xkv16,
                        _Float16* __restrict__ wq16, _Float16* __restrict__ wk16,
                        _Float16* __restrict__ wv16, _Float16* __restrict__ wo16)
{
    const int y = blockIdx.y;
    const int n = (y < 2) ? (4096 * 1024) : (1024 * 1024);
    int i = (blockIdx.x * 256 + threadIdx.x) * 8;
    if (i >= n) return;
    const float* in = (y == 0) ? x_q : (y == 1) ? x_kv : (y == 2) ? wq : (y == 3) ? wk : (y == 4) ? wv : wo;
    _Float16* out = (y == 0) ? xq16 : (y == 1) ? xkv16 : (y == 2) ? wq16 : (y == 3) ? wk16 : (y == 4) ? wv16 : wo16;
    float4 a = *(const float4*)(in + i);
    float4 b = *(const float4*)(in + i + 4);
    half8 h;
    h[0] = (_Float16)a.x; h[1] = (_Float16)a.y; h[2] = (_Float16)a.z; h[3] = (_Float16)a.w;
    h[4] = (_Float16)b.x; h[5] = (_Float16)b.y; h[6] = (_Float16)b.z; h[7] = (_Float16)b.w;
    *(half8*)(out + i) = h;
}

// ---------------- GEMM body: C[m,n] = (sum_k A[m,k]*W[n,k] + bias[n]) * osc ----------------
// Tile 64(M) x 128(N), BK=64, double-buffered LDS, one barrier per K-step.
// VT=true: write output transposed per-head for attention V.
template <typename OutT, bool VT>
__device__ __forceinline__ void gemm_body(
    const _Float16* __restrict__ A,
    const _Float16* __restrict__ W,
    const float* __restrict__ bias,
    OutT* __restrict__ C,
    int N, int K, int bm, int bn, float osc,
    _Float16* As, _Float16* Bs)   // As: [2][64*64], Bs: [2][128*64]
{
    const int tid = threadIdx.x;
    const int wv = tid >> 6;
    const int lane = tid & 63;
    const int lr = lane & 15;
    const int lk = lane >> 4;
    const int wm = wv >> 1, wn = wv & 1;

    auto stage = [&](int cb, int k0) {
#pragma unroll
        for (int i = 0; i < 2; ++i) {
            int chunk = i * 256 + tid;              // A tile 64x64
            int row = chunk >> 3, c8 = chunk & 7;
            gld_lds16(A + (size_t)(bm * 64 + row) * K + k0 + c8 * 8, &As[cb * 4096 + chunk * 8]);
        }
#pragma unroll
        for (int i = 0; i < 4; ++i) {
            int chunk = i * 256 + tid;              // B tile 128x64
            int row = chunk >> 3, c8 = chunk & 7;
            gld_lds16(W + (size_t)(bn * 128 + row) * K + k0 + c8 * 8, &Bs[cb * 8192 + chunk * 8]);
        }
    };

    f32x4 acc[2][4] = {};

    stage(0, 0);
    __syncthreads();

    for (int k2 = 0; k2 < K; k2 += 128) {
#pragma unroll
        for (int hf = 0; hf < 2; ++hf) {
            const int k0 = k2 + hf * 64;
            if (k0 + 64 < K) stage(hf ^ 1, k0 + 64);
#pragma unroll
            for (int kk = 0; kk < 2; ++kk) {
                half8 a[2], b[4];
#pragma unroll
                for (int m = 0; m < 2; ++m)
                    a[m] = *(const half8*)&As[hf * 4096 + (wm * 32 + m * 16 + lr) * 64 + kk * 32 + lk * 8];
#pragma unroll
                for (int n = 0; n < 4; ++n)
                    b[n] = *(const half8*)&Bs[hf * 8192 + (wn * 64 + n * 16 + lr) * 64 + kk * 32 + lk * 8];
#pragma unroll
                for (int m = 0; m < 2; ++m)
#pragma unroll
                    for (int n = 0; n < 4; ++n)
                        acc[m][n] = __builtin_amdgcn_mfma_f32_16x16x32_f16(a[m], b[n], acc[m][n], 0, 0, 0);
            }
            __syncthreads();
        }
    }

#pragma unroll
    for (int m = 0; m < 2; ++m) {
#pragma unroll
        for (int n = 0; n < 4; ++n) {
            int row0 = bm * 64 + wm * 32 + m * 16 + lk * 4;
            int col  = bn * 128 + wn * 64 + n * 16 + lr;
            float bb = bias[col];
            if (VT) {
                int b = row0 >> 11, l0 = row0 & 2047, h = col >> 6, dh = col & 63;
                half4 hv;
#pragma unroll
                for (int r = 0; r < 4; ++r) hv[r] = (_Float16)((acc[m][n][r] + bb) * osc);
                *(half4*)&C[(size_t)(((b * 16 + h) * 64 + dh)) * 2048 + l0] = hv;
            } else {
#pragma unroll
                for (int r = 0; r < 4; ++r) {
                    float v = (acc[m][n][r] + bb) * osc;
                    C[(size_t)(row0 + r) * N + col] = (OutT)v;
                }
            }
        }
    }
}

template <typename OutT>
__global__ __launch_bounds__(256) void gemm_bt(
    const _Float16* __restrict__ A, const _Float16* __restrict__ W,
    const float* __restrict__ bias, OutT* __restrict__ C,
    int M, int N, int K)
{
    __shared__ _Float16 As[2 * 64 * 64];
    __shared__ _Float16 Bs[2 * 128 * 64];
    const int nbn = N >> 7;
    gemm_body<OutT, false>(A, W, bias, C, N, K, blockIdx.x / nbn, blockIdx.x % nbn, 1.0f, As, Bs);
}

// QKV fused: blockIdx.y selects projection; Q pre-scaled by log2(e)/8; V written transposed.
__global__ __launch_bounds__(256) void gemm_qkv(
    const _Float16* __restrict__ xq, const _Float16* __restrict__ xkv,
    const _Float16* __restrict__ wqp, const _Float16* __restrict__ wkp, const _Float16* __restrict__ wvp,
    const float* __restrict__ bq, const float* __restrict__ bk, const float* __restrict__ bvv,
    _Float16* __restrict__ Qb, _Float16* __restrict__ Kb, _Float16* __restrict__ VbT)
{
    __shared__ _Float16 As[2 * 64 * 64];
    __shared__ _Float16 Bs[2 * 128 * 64];
    const int z = blockIdx.y;
    const _Float16* A = (z == 0) ? xq : xkv;
    const _Float16* W = (z == 0) ? wqp : (z == 1) ? wkp : wvp;
    const float* bias = (z == 0) ? bq : (z == 1) ? bk : bvv;
    const int bm = blockIdx.x >> 3, bn = blockIdx.x & 7;
    if (z == 2)
        gemm_body<_Float16, true>(A, W, bias, VbT, 1024, 1024, bm, bn, 1.0f, As, Bs);
    else
        gemm_body<_Float16, false>(A, W, bias, (z == 0) ? Qb : Kb, 1024, 1024, bm, bn,
                                   (z == 0) ? (0.125f * 1.44269504088896f) : 1.0f, As, Bs);
}

// ---------------- Flash attention (swapped QK^T, in-register softmax, dbuf, XCD swizzle) --------
// Q,K: (B*L, 1024) f16 (Q pre-scaled by log2e/8). VT: [b][h][dh=64][l=2048] f16.
// 1D grid 512 blocks, 8 waves; XCD swizzle: id=(b&7)*64+(b>>3) -> 4 heads per XCD (K/V L2-fit).
// S^T = mfma(K-frag, Q-frag); softmax in-register; P^T frag feeds 16x16x16 PV MFMA.
// K/V LDS double-buffered; one barrier per tile; defer-max rescale (THR=8, log2 domain).
__global__ __launch_bounds__(512, 4) void attn_fwd(
    const _Float16* __restrict__ Q,
    const _Float16* __restrict__ Kt,
    const _Float16* __restrict__ VT,
    _Float16* __restrict__ O)
{
    constexpr int KT = 128;
    __shared__ __align__(16) _Float16 Ks[2][KT * 64];   // [kv][d], chunk swz c8 ^= kv&7
    __shared__ __align__(16) _Float16 Vs[2][64 * KT];   // [d][kv], chunk swz c16 ^= d&15

    const int tid = threadIdx.x;
    const int wv = tid >> 6;
    const int lane = tid & 63;
    const int lr = lane & 15;
    const int lk = lane >> 4;
    const int id = ((blockIdx.x & 7) << 6) | (blockIdx.x >> 3);   // bijective XCD swizzle
    const int qb = id & 15;
    const int bh = id >> 4;
    const size_t base = (size_t)(bh >> 4) * (2048 * 1024) + (size_t)(bh & 15) * 64;
    const size_t vtbase = (size_t)bh * (64 * 2048);

    half8 qf[2];
    {
        const _Float16* qp = Q + base + (size_t)(qb * 128 + wv * 16 + lr) * 1024 + lk * 8;
        qf[0] = *(const half8*)qp;
        qf[1] = *(const half8*)(qp + 32);
    }

    auto stage = [&](int cb, int kt) {
#pragma unroll
        for (int i = 0; i < 2; ++i) {
            int chunk = i * 512 + tid;              // K tile 128x64
            int row = chunk >> 3, c8 = chunk & 7;
            int c8s = c8 ^ (row & 7);
            gld_lds16(Kt + base + (size_t)(kt + row) * 1024 + c8s * 8, &Ks[cb][chunk * 8]);
        }
#pragma unroll
        for (int i = 0; i < 2; ++i) {
            int chunk = i * 512 + tid;              // V^T tile 64x128
            int row = chunk >> 4, c16 = chunk & 15; // row = d
            int c16s = c16 ^ (row & 15);
            gld_lds16(VT + vtbase + (size_t)row * 2048 + kt + c16s * 8, &Vs[cb][chunk * 8]);
        }
    };

    float mr = -1e30f, ls = 0.f;
    f32x4 o[4] = {};

    stage(0, 0);
    __syncthreads();

    for (int kt2 = 0; kt2 < 2048; kt2 += 2 * KT) {
#pragma unroll
        for (int hf = 0; hf < 2; ++hf) {
            const int kt = kt2 + hf * KT;
            if (kt + KT < 2048) stage(hf ^ 1, kt + KT);

            // kt-invariant lane addresses (compiler CSEs; hf folds into offset imm)
            const _Float16* kb0 = &Ks[hf][lr * 64 + ((lk     ^ (lr & 7)) << 3)];
            const _Float16* kb1 = &Ks[hf][lr * 64 + (((4|lk) ^ (lr & 7)) << 3)];
            const _Float16* vbb = &Vs[hf][lr * 128 + ((lk & 1) << 2)];

            // S^T = K Q^T
            f32x4 s[8] = {};
#pragma unroll
            for (int n = 0; n < 8; ++n) {
                half8 a0 = *(const half8*)(kb0 + n * 1024);
                s[n] = __builtin_amdgcn_mfma_f32_16x16x32_f16(a0, qf[0], s[n], 0, 0, 0);
            }
#pragma unroll
            for (int n = 0; n < 8; ++n) {
                half8 a1 = *(const half8*)(kb1 + n * 1024);
                s[n] = __builtin_amdgcn_mfma_f32_16x16x32_f16(a1, qf[1], s[n], 0, 0, 0);
            }

            // in-register softmax (exp2 domain): lane owns q=lr, 32 kv values
            float tm = -1e30f;
#pragma unroll
            for (int n = 0; n < 8; ++n)
#pragma unroll
                for (int r = 0; r < 4; ++r) tm = fmaxf(tm, s[n][r]);
            tm = fmaxf(tm, __shfl_xor(tm, 16));
            tm = fmaxf(tm, __shfl_xor(tm, 32));

            if (!__all(tm <= mr + 8.0f)) {
                float mn = fmaxf(mr, tm);
                float al = __builtin_amdgcn_exp2f(mr - mn);
                mr = mn;
                ls *= al;
#pragma unroll
                for (int nd = 0; nd < 4; ++nd)
#pragma unroll
                    for (int r = 0; r < 4; ++r) o[nd][r] *= al;
            }

            float rs = 0.f;
            half4 pf[8];
#pragma unroll
            for (int n = 0; n < 8; ++n) {
                float p0 = __builtin_amdgcn_exp2f(s[n][0] - mr);
                float p1 = __builtin_amdgcn_exp2f(s[n][1] - mr);
                float p2 = __builtin_amdgcn_exp2f(s[n][2] - mr);
                float p3 = __builtin_amdgcn_exp2f(s[n][3] - mr);
                rs += (p0 + p1) + (p2 + p3);
                fp16x2 lo = __builtin_amdgcn_cvt_pkrtz(p0, p1);
                fp16x2 hi = __builtin_amdgcn_cvt_pkrtz(p2, p3);
                fp16x4 pv4 = __builtin_shufflevector(lo, hi, 0, 1, 2, 3);
                pf[n] = __builtin_bit_cast(half4, pv4);
            }
            rs += __shfl_xor(rs, 16);
            rs += __shfl_xor(rs, 32);
            ls += rs;

            // O^T += V^T · P^T
#pragma unroll
            for (int kvb = 0; kvb < 8; ++kvb) {
                int co = ((((kvb << 1) | (lk >> 1)) ^ lr) << 3) - (lr << 3);  // delta vs vbb's col term
#pragma unroll
                for (int nd = 0; nd < 4; ++nd) {
                    half4 va = *(const half4*)&Vs[hf][lr * 128 + ((((kvb << 1) | (lk >> 1)) ^ lr) << 3) + ((lk & 1) << 2) + nd * 2048];
                    o[nd] = __builtin_amdgcn_mfma_f32_16x16x16f16(va, pf[kvb], o[nd], 0, 0, 0);
                }
            }
            (void)vbb;

            __syncthreads();
        }
    }

    // O^T[d][q] per lane -> store: q = lr row, d = nd*16 + lk*4 + r (half4 per nd)
    const float inv = 1.0f / ls;
    const size_t orow = base + (size_t)(qb * 128 + wv * 16 + lr) * 1024;
#pragma unroll
    for (int nd = 0; nd < 4; ++nd) {
        half4 hv;
#pragma unroll
        for (int r = 0; r < 4; ++r) hv[r] = (_Float16)(o[nd][r] * inv);
        *(half4*)&O[orow + nd * 16 + lk * 4] = hv;
    }
}

extern "C" void kernel_launch(void* const* d_in, const int* in_sizes, int n_in,
                              void* d_out, int out_size, void* d_ws, size_t ws_size,
                              hipStream_t stream) {
    const float* x_q  = (const float*)d_in[0];
    const float* x_kv = (const float*)d_in[1];
    const float* wq   = (const float*)d_in[2];
    const float* bq   = (const float*)d_in[3];
    const float* wk   = (const float*)d_in[4];
    const float* bk   = (const float*)d_in[5];
    const float* wvp  = (const float*)d_in[6];
    const float* bv   = (const float*)d_in[7];
    const float* wo   = (const float*)d_in[8];
    const float* bo   = (const float*)d_in[9];
    float* out = (float*)d_out;

    const size_t MX = (size_t)4096 * 1024;
    const size_t WX = (size_t)1024 * 1024;
    _Float16* ws    = (_Float16*)d_ws;
    _Float16* xq16  = ws;
    _Float16* xkv16 = xq16 + MX;
    _Float16* wq16  = xkv16 + MX;
    _Float16* wk16  = wq16 + WX;
    _Float16* wv16  = wk16 + WX;
    _Float16* wo16  = wv16 + WX;
    _Float16* Qb    = wo16 + WX;
    _Float16* Kb    = Qb + MX;
    _Float16* VbT   = Kb + MX;
    _Float16* AO    = VbT + MX;

    cvt_all<<<dim3(2048, 6), 256, 0, stream>>>(x_q, x_kv, wq, wk, wvp, wo,
                                               xq16, xkv16, wq16, wk16, wv16, wo16);

    gemm_qkv<<<dim3(512, 3), 256, 0, stream>>>(xq16, xkv16, wq16, wk16, wv16,
                                               bq, bk, bv, Qb, Kb, VbT);

    attn_fwd<<<dim3(512), 512, 0, stream>>>(Qb, Kb, VbT, AO);

    gemm_bt<float><<<dim3(512), 256, 0, stream>>>(AO, wo16, bo, out, 4096, 1024, 1024);
}